// Round 22
// baseline (41.053 us; speedup 1.0000x reference)
//
#include <hip/hip_runtime.h>

#define KC   21      // num classes
#define BB   8       // batch
#define CC   256     // feat channels
#define HWP  65536   // 256*256 output pixels per image
#define SRC  4096    // 64*64 source pixels
#define NS   64      // chunks: one full source row (64 p) each
#define PC   64      // p per chunk

// d_ws layout: L = 524288 BYTES [0, 524288) | partialw f32 @ byte 524288
// (8*64*21 = 10752 floats) | partial f32 @ float idx 141824 (11 MB). Disjoint.
#define WSF_PARTW 131072
#define WSF_PART  (WSF_PARTW + BB*NS*KC)     // 141824

// ---- k1: per-pixel argmax + gt-match -> label map (EXACT R21, proven) -------
__global__ __launch_bounds__(256, 2)
void k1_classify(const float* __restrict__ preds,
                 const int*   __restrict__ masks,
                 unsigned char* __restrict__ L,
                 float* __restrict__ out)
{
    int tid = threadIdx.x;
    if (blockIdx.x == 0) {
        float4* o4 = reinterpret_cast<float4*>(out);
#pragma unroll
        for (int i = 0; i < (KC * CC / 4 + 255) / 256; ++i) {
            int j = tid + i * 256;
            if (j < KC * CC / 4) o4[j] = make_float4(0.f, 0.f, 0.f, 0.f);
        }
    }

    int idx = blockIdx.x * 256 + tid;            // over B*HWP/4 = 131072
    int b   = idx >> 14;
    int hw4 = (idx & 16383) << 2;

    const float* pb = preds + (size_t)b * KC * HWP + hw4;
    float va[4][KC];
#pragma unroll
    for (int k = 0; k < KC; ++k) {
        float4 t = *reinterpret_cast<const float4*>(pb + (size_t)k * HWP);
        va[0][k] = t.x; va[1][k] = t.y; va[2][k] = t.z; va[3][k] = t.w;
    }

    int4 mm = *reinterpret_cast<const int4*>(masks + b * HWP + hw4);
    int mk[4] = { mm.x, mm.y, mm.z, mm.w };

    uchar4 r;
    unsigned char* rp = reinterpret_cast<unsigned char*>(&r);
#pragma unroll
    for (int j = 0; j < 4; ++j) {
        float best = va[j][0];
        int   bi   = 0;
#pragma unroll
        for (int k = 1; k < KC; ++k) {
            if (va[j][k] > best) { best = va[j][k]; bi = k; }  // first-index ties
        }
        rp[j] = (mk[j] == bi) ? (unsigned char)bi : (unsigned char)255;
    }
    *reinterpret_cast<uchar4*>(L + (size_t)b * HWP + hw4) = r;
}

// ---- k2: full-row blocks, 256 thr, thread owns all 64 p (no psub/scr) -------
// Grid (64,8) = 512 blocks -> occupancy is GRID-limited to 2 blocks/CU at any
// block size, so 256 thr with f[64] in regs removes the psub combine (scr,
// 1 barrier, 42 LDS ops/thread) at identical per-CU wave-instruction totals.
// LDS 5.25 KB. launch_bounds(256,2): VGPR cap 256 >> ~110 demand (no spill).
__global__ __launch_bounds__(256, 2)
void k2_contract(const float* __restrict__ feats,      // [B][C][SRC]
                 const unsigned char* __restrict__ L,  // [B][256][256]
                 float* __restrict__ partial,          // [B][NS][K][C] f32
                 float* __restrict__ partialw)         // [B][NS][K]
{
    __shared__ float ws[KC * PC];     // [21][64] = 5.25 KB gather target
    int s = blockIdx.x, b = blockIdx.y;   // s = source row y
    int tid = threadIdx.x;            // 0..255 = channel
    int p0 = s * PC;

    for (int t = tid; t < KC * PC / 4; t += 256)      // zero ws: 336 float4
        *reinterpret_cast<float4*>(ws + t * 4) = make_float4(0.f, 0.f, 0.f, 0.f);

    // feats: own full row to registers (16 independent float4 loads; their
    // latency hides under the gather phase)
    float f[PC];
    {
        const float* frow = feats + (size_t)(b * CC + tid) * SRC + p0;
#pragma unroll
        for (int q = 0; q < PC / 4; ++q) {
            float4 t = *reinterpret_cast<const float4*>(frow + q * 4);
            f[q * 4 + 0] = t.x; f[q * 4 + 1] = t.y;
            f[q * 4 + 2] = t.z; f[q * 4 + 3] = t.w;
        }
    }
    __syncthreads();                  // ws zeroed

    // gather labels: 8 hi-res rows x 256 cols (full width, no col clipping)
    {
        int r = tid >> 5, cb = tid & 31;              // 8 rows x 32 threads
        int h = 4 * s - 2 + r;
        if ((unsigned)h < 256u) {
            float sy = h * 0.25f - 0.375f;
            int   yt = (int)floorf(sy);
            float wy = sy - (float)yt;
            int ya = yt < 0 ? 0 : yt;
            int yb = yt + 1 > 63 ? 63 : yt + 1;
            float wyy = ((ya == s) ? (1.f - wy) : 0.f) + ((yb == s) ? wy : 0.f);
            if (wyy != 0.f) {
                const unsigned char* Lrow = L + ((size_t)b << 16) + ((size_t)h << 8);
#pragma unroll
                for (int j = 0; j < 8; ++j) {
                    int w = cb + j * 32;              // all 256 cols
                    int k = Lrow[w];
                    if (k < KC) {
                        float sx = w * 0.25f - 0.375f;
                        int   xt = (int)floorf(sx);
                        float wx = sx - (float)xt;
                        int xa = xt < 0 ? 0 : xt;
                        int xb = xt + 1 > 63 ? 63 : xt + 1;
                        atomicAdd(&ws[k * PC + xa], wyy * (1.f - wx));  // dyadic-exact
                        atomicAdd(&ws[k * PC + xb], wyy * wx);
                    }
                }
            }
        }
    }
    __syncthreads();                  // ws final

    // exact per-chunk class-count contribution (rotated reads)
    float swcnt = 0.f;
    if (tid < KC) {
#pragma unroll
        for (int p = 0; p < PC; ++p) swcnt += ws[tid * PC + ((p + tid * 3) & (PC - 1))];
    }

    float acc[KC];
#pragma unroll
    for (int k = 0; k < KC; ++k) {    // fully unrolled, static idx
        const float* wk = ws + k * PC;
        float a0 = 0.f, a1 = 0.f, a2 = 0.f, a3 = 0.f;
#pragma unroll
        for (int q = 0; q < PC / 4; ++q) {
            float4 w4 = *reinterpret_cast<const float4*>(wk + q * 4);  // uniform b128
            a0 += w4.x * f[q * 4 + 0];
            a1 += w4.y * f[q * 4 + 1];
            a2 += w4.z * f[q * 4 + 2];
            a3 += w4.w * f[q * 4 + 3];
        }
        acc[k] = (a0 + a1) + (a2 + a3);
    }

    float* op = partial + ((size_t)(b * NS + s)) * KC * CC + tid;
#pragma unroll
    for (int k = 0; k < KC; ++k)
        op[(size_t)k * CC] = acc[k];              // coalesced 1KB store per k

    if (tid < KC)
        partialw[(size_t)(b * NS + s) * KC + tid] = swcnt;  // dyadic-exact
}

// ---- k3: reduce 64 chunks, derive exact counts, normalize (EXACT R21) -------
__global__ __launch_bounds__(256)
void k3_finalize(const float* __restrict__ partial,   // [B][NS][K][C]
                 const float* __restrict__ partialw,  // [B][NS][K]
                 float* __restrict__ out)             // [K][C], zeroed by k1
{
    int k = blockIdx.x, b = blockIdx.y;
    int tid = threadIdx.x;

    const float* base = partial + ((size_t)(b * NS) * KC + k) * CC + tid;
    float acc = 0.f;
#pragma unroll 8
    for (int s = 0; s < NS; ++s) acc += base[(size_t)s * KC * CC];

    __shared__ float red;
    if (tid < 64) {                   // single-wave reduce of 64 chunk counts
        float v = partialw[(size_t)(b * NS + tid) * KC + k];
#pragma unroll
        for (int off = 32; off; off >>= 1) v += __shfl_down(v, off);
        if (tid == 0) red = v;
    }
    __syncthreads();
    float cnt = red;                  // dyadic-exact pixel count

    atomicAdd(&out[k * CC + tid], acc / (8.f * (cnt + 1e-6f)));
}

extern "C" void kernel_launch(void* const* d_in, const int* in_sizes, int n_in,
                              void* d_out, int out_size, void* d_ws, size_t ws_size,
                              hipStream_t stream) {
    const float* feats = (const float*)d_in[0];   // [8,256,64,64]
    const float* preds = (const float*)d_in[1];   // [8,21,256,256]
    const int*   masks = (const int*)  d_in[2];   // [8,256,256]
    float* out = (float*)d_out;                   // [21,256]

    float* wsf = (float*)d_ws;
    unsigned char* L = (unsigned char*)d_ws;      // 524288 bytes, fully written by k1
    float* partialw = wsf + WSF_PARTW;            // byte 524288: disjoint from L
    float* partial  = wsf + WSF_PART;

    k1_classify<<<(BB * HWP / 4) / 256, 256, 0, stream>>>(preds, masks, L, out);
    k2_contract<<<dim3(NS, BB), 256, 0, stream>>>(feats, L, partial, partialw);
    k3_finalize<<<dim3(KC, BB), 256, 0, stream>>>(partial, partialw, out);
}

// Round 23
// 31.763 us; speedup vs baseline: 1.2925x; 1.2925x over previous
//
#include <hip/hip_runtime.h>

#define KC   21      // num classes
#define BB   8       // batch
#define CC   256     // feat channels
#define HWP  65536   // 256*256 output pixels per image
#define SRC  4096    // 64*64 source pixels
#define NS   32      // chunks: TWO full source rows (128 p) each
#define PC   128     // p per chunk

// d_ws layout: L = 524288 BYTES [0, 524288) | partialw f32 @ byte 524288
// (8*32*21 = 5376 floats) | partial f32 @ float idx 139264 (5.5 MB). Disjoint.
#define WSF_PARTW 131072
#define WSF_PART  139264

// ---- k1: per-pixel argmax + gt-match -> label map (EXACT R21, proven) -------
__global__ __launch_bounds__(256, 2)
void k1_classify(const float* __restrict__ preds,
                 const int*   __restrict__ masks,
                 unsigned char* __restrict__ L,
                 float* __restrict__ out)
{
    int tid = threadIdx.x;
    if (blockIdx.x == 0) {
        float4* o4 = reinterpret_cast<float4*>(out);
#pragma unroll
        for (int i = 0; i < (KC * CC / 4 + 255) / 256; ++i) {
            int j = tid + i * 256;
            if (j < KC * CC / 4) o4[j] = make_float4(0.f, 0.f, 0.f, 0.f);
        }
    }

    int idx = blockIdx.x * 256 + tid;            // over B*HWP/4 = 131072
    int b   = idx >> 14;
    int hw4 = (idx & 16383) << 2;

    const float* pb = preds + (size_t)b * KC * HWP + hw4;
    float va[4][KC];
#pragma unroll
    for (int k = 0; k < KC; ++k) {
        float4 t = *reinterpret_cast<const float4*>(pb + (size_t)k * HWP);
        va[0][k] = t.x; va[1][k] = t.y; va[2][k] = t.z; va[3][k] = t.w;
    }

    int4 mm = *reinterpret_cast<const int4*>(masks + b * HWP + hw4);
    int mk[4] = { mm.x, mm.y, mm.z, mm.w };

    uchar4 r;
    unsigned char* rp = reinterpret_cast<unsigned char*>(&r);
#pragma unroll
    for (int j = 0; j < 4; ++j) {
        float best = va[j][0];
        int   bi   = 0;
#pragma unroll
        for (int k = 1; k < KC; ++k) {
            if (va[j][k] > best) { best = va[j][k]; bi = k; }  // first-index ties
        }
        rp[j] = (mk[j] == bi) ? (unsigned char)bi : (unsigned char)255;
    }
    *reinterpret_cast<uchar4*>(L + (size_t)b * HWP + hw4) = r;
}

// ---- k2: 2-row chunks, 1024 thr -> partial halved to 5.5 MB at 16 waves/CU --
// Grid (32,8) = 256 blocks = 1/CU x 16 waves (the proven-required occupancy;
// R22's 8 waves/CU = +8 us). Gather = R19's 2-row pattern (bit-exact there).
// Thread (cp=tid&255, psub=tid>>8 quarter of 128 p); 4-way combine via scr.
__global__ __launch_bounds__(1024, 4)
void k2_contract(const float* __restrict__ feats,      // [B][C][SRC]
                 const unsigned char* __restrict__ L,  // [B][256][256]
                 float* __restrict__ partial,          // [B][NS][K][C] f32
                 float* __restrict__ partialw)         // [B][NS][K]
{
    __shared__ float ws[KC * PC];         // [21][128] = 10.5 KB gather target
    __shared__ float scr[3 * KC * CC];    // 64.5 KB psub-combine scratch
    int s = blockIdx.x, b = blockIdx.y;   // s = 2-row chunk (rows 2s, 2s+1)
    int tid = threadIdx.x;                // 0..1023
    int p0 = s * PC;
    int ybase = 2 * s;

    int cp   = tid & 255;                 // channel
    int psub = tid >> 8;                  // wave-uniform p-quarter (0..3)
    int pw   = psub * 32;

    for (int t = tid; t < KC * PC / 4; t += 1024)     // zero ws: 672 float4
        *reinterpret_cast<float4*>(ws + t * 4) = make_float4(0.f, 0.f, 0.f, 0.f);

    // feats: own 32-p quarter straight to registers (hidden under gather)
    float f[32];
    {
        const float* frow = feats + (size_t)(b * CC + cp) * SRC + p0 + pw;
#pragma unroll
        for (int q = 0; q < 8; ++q) {
            float4 t = *reinterpret_cast<const float4*>(frow + q * 4);
            f[q * 4 + 0] = t.x; f[q * 4 + 1] = t.y;
            f[q * 4 + 2] = t.z; f[q * 4 + 3] = t.w;
        }
    }
    __syncthreads();                      // ws zeroed

    // gather labels: 12 hi-res rows [8s-2, 8s+9] x 256 cols (R19 pattern)
    {
        int r = tid >> 6, cb = tid & 63;  // 16 groups x 64 threads; use r < 12
        int h = 8 * s - 2 + r;
        if (r < 12 && (unsigned)h < 256u) {
            float sy = h * 0.25f - 0.375f;
            int   yt = (int)floorf(sy);
            float wy = sy - (float)yt;
            int ya = yt < 0 ? 0 : yt;
            int yb = yt + 1 > 63 ? 63 : yt + 1;
            float wyy0 = ((ya == ybase)     ? (1.f - wy) : 0.f) + ((yb == ybase)     ? wy : 0.f);
            float wyy1 = ((ya == ybase + 1) ? (1.f - wy) : 0.f) + ((yb == ybase + 1) ? wy : 0.f);
            if (wyy0 != 0.f || wyy1 != 0.f) {
                const unsigned char* Lrow = L + ((size_t)b << 16) + ((size_t)h << 8);
#pragma unroll
                for (int j = 0; j < 4; ++j) {
                    int w = cb + j * 64;              // all 256 cols
                    int k = Lrow[w];
                    if (k < KC) {
                        float sx = w * 0.25f - 0.375f;
                        int   xt = (int)floorf(sx);
                        float wx = sx - (float)xt;
                        int xa = xt < 0 ? 0 : xt;
                        int xb = xt + 1 > 63 ? 63 : xt + 1;
                        float* wk = ws + k * PC;
                        if (wyy0 != 0.f) {                       // row 2s
                            atomicAdd(wk + xa, wyy0 * (1.f - wx));   // dyadic-exact
                            atomicAdd(wk + xb, wyy0 * wx);
                        }
                        if (wyy1 != 0.f) {                       // row 2s+1
                            atomicAdd(wk + 64 + xa, wyy1 * (1.f - wx));
                            atomicAdd(wk + 64 + xb, wyy1 * wx);
                        }
                    }
                }
            }
        }
    }
    __syncthreads();                      // ws final

    // exact per-chunk class-count contribution (rotated reads)
    float swcnt = 0.f;
    if (tid < KC) {
#pragma unroll
        for (int i = 0; i < PC; ++i)
            swcnt += ws[tid * PC + ((i + tid * 8) & (PC - 1))];
    }

    float acc[KC];
#pragma unroll
    for (int k = 0; k < KC; ++k) {        // fully unrolled, static idx
        const float* wk = ws + k * PC + pw;
        float a0 = 0.f, a1 = 0.f, a2 = 0.f, a3 = 0.f;
#pragma unroll
        for (int q = 0; q < 8; ++q) {
            float4 w4 = *reinterpret_cast<const float4*>(wk + q * 4);  // uniform b128
            a0 += w4.x * f[q * 4 + 0];
            a1 += w4.y * f[q * 4 + 1];
            a2 += w4.z * f[q * 4 + 2];
            a3 += w4.w * f[q * 4 + 3];
        }
        acc[k] = (a0 + a1) + (a2 + a3);
    }

    // 4-way psub combine: psub 1..3 park in scr, psub0 sums and stores
    if (psub >= 1) {
        float* sp = scr + (psub - 1) * (KC * CC);
#pragma unroll
        for (int k = 0; k < KC; ++k) sp[k * CC + cp] = acc[k];
    }
    __syncthreads();
    if (psub == 0) {
        float* op = partial + ((size_t)(b * NS + s)) * KC * CC + cp;
#pragma unroll
        for (int k = 0; k < KC; ++k) {
            float v = acc[k] + scr[k * CC + cp]
                             + scr[KC * CC + k * CC + cp]
                             + scr[2 * KC * CC + k * CC + cp];
            op[(size_t)k * CC] = v;       // coalesced 1KB store per k
        }
    }

    if (tid < KC)
        partialw[(size_t)(b * NS + s) * KC + tid] = swcnt;  // dyadic-exact
}

// ---- k3: reduce 32 chunks, derive exact counts, normalize -------------------
__global__ __launch_bounds__(256)
void k3_finalize(const float* __restrict__ partial,   // [B][NS][K][C]
                 const float* __restrict__ partialw,  // [B][NS][K]
                 float* __restrict__ out)             // [K][C], zeroed by k1
{
    int k = blockIdx.x, b = blockIdx.y;
    int tid = threadIdx.x;

    const float* base = partial + ((size_t)(b * NS) * KC + k) * CC + tid;
    float acc = 0.f;
#pragma unroll 8
    for (int s = 0; s < NS; ++s) acc += base[(size_t)s * KC * CC];

    __shared__ float red;
    if (tid < 64) {                       // single-wave reduce of 32 counts
        float v = (tid < NS) ? partialw[(size_t)(b * NS + tid) * KC + k] : 0.f;
#pragma unroll
        for (int off = 32; off; off >>= 1) v += __shfl_down(v, off);
        if (tid == 0) red = v;
    }
    __syncthreads();
    float cnt = red;                      // dyadic-exact pixel count

    atomicAdd(&out[k * CC + tid], acc / (8.f * (cnt + 1e-6f)));
}

extern "C" void kernel_launch(void* const* d_in, const int* in_sizes, int n_in,
                              void* d_out, int out_size, void* d_ws, size_t ws_size,
                              hipStream_t stream) {
    const float* feats = (const float*)d_in[0];   // [8,256,64,64]
    const float* preds = (const float*)d_in[1];   // [8,21,256,256]
    const int*   masks = (const int*)  d_in[2];   // [8,256,256]
    float* out = (float*)d_out;                   // [21,256]

    float* wsf = (float*)d_ws;
    unsigned char* L = (unsigned char*)d_ws;      // 524288 bytes, fully written by k1
    float* partialw = wsf + WSF_PARTW;            // byte 524288: disjoint from L
    float* partial  = wsf + WSF_PART;

    k1_classify<<<(BB * HWP / 4) / 256, 256, 0, stream>>>(preds, masks, L, out);
    k2_contract<<<dim3(NS, BB), 1024, 0, stream>>>(feats, L, partial, partialw);
    k3_finalize<<<dim3(KC, BB), 256, 0, stream>>>(partial, partialw, out);
}